// Round 11
// baseline (35.884 us; speedup 1.0000x reference)
//
#include <hip/hip_runtime.h>

// out[b,o] = sum_h W2[o,h]*leaky(h) + b2[o],  h = W1[o]·x[b] + b1[o]
// leaky(t) = 0.6t + 0.4|t|
//   out[b,o] = 0.6(v[o]·x[b] + c0[o]) + b2[o] + sum_h (0.4 W2[o,h])|h|
// R11: LDS-BW wall removed. All weights in REGISTERS via 4-way H-split
// (wave w owns h in [w*128,(w+1)*128)): A1 16 + W2 16 + b1(C-op) 32 VGPR.
// Inner loop has ZERO LDS reads (prior rounds: ~2 GB LDS reads ~= 25 us at
// 69 TB/s — the invariant across R4-R10). Per job: 1 coalesced x load,
// 8 mfma16 (K=16 exact, b1 via f32 C) + 4 mfma32 (verified w2f k->h perm),
// cross-wave reduce = 64 floats via LDS + 1 barrier. 1024x256, one round.

#define B_DIM 32768
#define I_DIM 16
#define O_DIM 16
#define H_DIM 512

typedef _Float16 f16x4 __attribute__((ext_vector_type(4)));
typedef _Float16 f16x8 __attribute__((ext_vector_type(8)));
typedef __fp16   h16x2 __attribute__((ext_vector_type(2)));   // cvt_pkrtz native
typedef float    f32x4 __attribute__((ext_vector_type(4)));
typedef int      i32x2 __attribute__((ext_vector_type(2)));
typedef int      i32x4 __attribute__((ext_vector_type(4)));

// ws layout (bytes)
#define A1F_OFF  0                   // [16 o][32 ct][64 l][4 f16] = 256 KiB
#define W2F_OFF  (256 * 1024)        // [16 o][16 p][64 l][8 f16] = 256 KiB
#define VL_OFF   (512 * 1024)        // [16 o][64 l][4 f16] = 8 KiB
#define C0_OFF   (521 * 1024)        // 16 floats

// --- prep -------------------------------------------------------------------
// blk [0,128)  : W1 -> stage1-A fragments (f16x4 per lane per ct)
// blk [128,192): W2 -> stage2-B fragments (0.4-scaled, k->h permutation)
// blk [192,208): v, c0
__global__ void prep_all(const float* __restrict__ W1, const float* __restrict__ b1,
                         const float* __restrict__ W2, const float* __restrict__ b2,
                         ushort* __restrict__ a1f, ushort* __restrict__ w2f,
                         ushort* __restrict__ vl, float* __restrict__ c0b2) {
    int blk = blockIdx.x;
    if (blk < 128) {
        int t = blk * 256 + threadIdx.x;          // [o][ct][lane]
        int l = t & 63, ct = (t >> 6) & 31, o = t >> 11;
        int row = l & 15, kg = l >> 4;
        f16x4 v;
#pragma unroll
        for (int j = 0; j < 4; ++j)
            v[j] = (_Float16)W1[(size_t)(o * H_DIM + ct * 16 + row) * I_DIM + kg * 4 + j];
        *reinterpret_cast<f16x4*>(a1f + (size_t)t * 4) = v;
    } else if (blk < 192) {
        // B-frag x32: k=kg*8+j -> h = p*32 + ((j>>2)&1)*16 + kg*4 + (j&3)
        int t = (blk - 128) * 256 + threadIdx.x;  // [o][p][lane]
        int l = t & 63, p = (t >> 6) & 15, o = t >> 10;
        int kg = l >> 4;
        f16x8 v;
#pragma unroll
        for (int j = 0; j < 8; ++j) {
            int h = p * 32 + ((j >> 2) & 1) * 16 + kg * 4 + (j & 3);
            v[j] = (_Float16)(0.4f * W2[o * H_DIM + h]);
        }
        *reinterpret_cast<f16x8*>(w2f + (size_t)t * 8) = v;
    } else {
        // per-o: v[i] = sum_h W2[h]W1[h,i];  c0b2 = 0.6*sum_h W2[h]b1[h] + b2
        __shared__ float red[256];
        __shared__ float v_sm[16];
        const int o = blk - 192, t = threadIdx.x;
        const int i = t & 15, hc = t >> 4;
        float acc = 0.f;
        for (int hh = 0; hh < 32; ++hh) {
            int h = hc * 32 + hh;
            acc = fmaf(W2[o * H_DIM + h], W1[(size_t)(o * H_DIM + h) * I_DIM + i], acc);
        }
        red[t] = acc;
        __syncthreads();
        if (t < 16) {
            float s = 0.f;
#pragma unroll
            for (int k = 0; k < 16; ++k) s += red[t + 16 * k];
            v_sm[t] = 0.6f * s;
        }
        float cacc = 0.f;
        for (int h = t; h < H_DIM; h += 256) cacc += W2[o * H_DIM + h] * b1[o * H_DIM + h];
        __syncthreads();
        red[t] = cacc;
        __syncthreads();
        if (t == 0) {
            float s = 0.f;
            for (int k = 0; k < 256; ++k) s += red[k];
            c0b2[o] = 0.6f * s + b2[o];
        }
        if (t < 64) {
            int kg = t >> 4;
            f16x4 v;
#pragma unroll
            for (int j = 0; j < 4; ++j) v[j] = (_Float16)v_sm[kg * 4 + j];
            *reinterpret_cast<f16x4*>(vl + (size_t)(o * 64 + t) * 4) = v;
        }
    }
}

// --- main -------------------------------------------------------------------
// 1024 blocks x 256 thr (4 waves) = 4 blocks/CU, one round.
// o = blk&15, grp = blk>>4 (64 per o); block covers tiles grp*32..+32.
// Wave w owns h-slice [w*128,(w+1)*128); per job cross-wave reduce via LDS.
__global__ __launch_bounds__(256, 4) void mlp_main(
    const float* __restrict__ x, const ushort* __restrict__ a1f_u,
    const ushort* __restrict__ w2f_u, const ushort* __restrict__ vl_u,
    const float* __restrict__ c0b2, const float* __restrict__ b1,
    float* __restrict__ out) {
    __shared__ float smred[2][64];

    const int tid = threadIdx.x;
    const int o   = blockIdx.x & 15;
    const int grp = blockIdx.x >> 4;
    const int lane = tid & 63, w = tid >> 6;
    const int col = lane & 15, kg = lane >> 4;

    // ---- weights -> registers (once per block; ws is L2-resident) ----
    const f16x4* ga = reinterpret_cast<const f16x4*>(a1f_u)
                    + ((size_t)(o * 32 + w * 8) * 64 + lane);
    f16x4 A1r[8];
#pragma unroll
    for (int c = 0; c < 8; ++c) A1r[c] = ga[c * 64];
    const f16x8* gw = reinterpret_cast<const f16x8*>(w2f_u)
                    + ((size_t)(o * 16 + w * 4) * 64 + lane);
    f16x8 W2r[4];
#pragma unroll
    for (int q = 0; q < 4; ++q) W2r[q] = gw[q * 64];
    f32x4 b1r[8];
#pragma unroll
    for (int c = 0; c < 8; ++c)
        b1r[c] = *reinterpret_cast<const f32x4*>(b1 + o * H_DIM + (w * 8 + c) * 16 + kg * 4);
    const f16x4 vlf = reinterpret_cast<const f16x4*>(vl_u)[o * 64 + lane];
    const float c0 = c0b2[o];
    const f32x4 linC = {c0, c0, c0, c0};
    const f32x4 zero = {0.f, 0.f, 0.f, 0.f};

    for (int j = 0; j < 32; ++j) {
        const int tile = grp * 32 + j;
        // x: coalesced f32x4 (1 KB/wave), fold to f16 (2 cvt)
        const f32x4 xr = *reinterpret_cast<const f32x4*>(
            x + (size_t)(tile * 16 + col) * I_DIM + kg * 4);
        h16x2 q0 = __builtin_amdgcn_cvt_pkrtz(xr[0], xr[1]);
        h16x2 q1 = __builtin_amdgcn_cvt_pkrtz(xr[2], xr[3]);
        i32x2 xi; xi[0] = __builtin_bit_cast(int, q0); xi[1] = __builtin_bit_cast(int, q1);
        const f16x4 xf = __builtin_bit_cast(f16x4, xi);

        // acc init: wave 0 carries the linear part (wave-uniform branch)
        f32x4 acc;
        if (w == 0) acc = __builtin_amdgcn_mfma_f32_16x16x16f16(xf, vlf, linC, 0, 0, 0);
        else        acc = zero;

#pragma unroll
        for (int q = 0; q < 4; ++q) {
            // stage1 (K=16 exact): d[r] = h[w*128 + q*32 (+16) + kg*4+r], b=col
            f32x4 d0 = __builtin_amdgcn_mfma_f32_16x16x16f16(A1r[2 * q],     xf, b1r[2 * q],     0, 0, 0);
            f32x4 d1 = __builtin_amdgcn_mfma_f32_16x16x16f16(A1r[2 * q + 1], xf, b1r[2 * q + 1], 0, 0, 0);
            // pack |d0|,|d1| -> stage2-A (k order matches w2f permutation)
            h16x2 p0 = __builtin_amdgcn_cvt_pkrtz(fabsf(d0[0]), fabsf(d0[1]));
            h16x2 p1 = __builtin_amdgcn_cvt_pkrtz(fabsf(d0[2]), fabsf(d0[3]));
            h16x2 p2 = __builtin_amdgcn_cvt_pkrtz(fabsf(d1[0]), fabsf(d1[1]));
            h16x2 p3 = __builtin_amdgcn_cvt_pkrtz(fabsf(d1[2]), fabsf(d1[3]));
            i32x4 ai;
            ai[0] = __builtin_bit_cast(int, p0); ai[1] = __builtin_bit_cast(int, p1);
            ai[2] = __builtin_bit_cast(int, p2); ai[3] = __builtin_bit_cast(int, p3);
            f16x8 A2 = __builtin_bit_cast(f16x8, ai);
            // stage2 (K=32): acc += 0.4 * sum_{32 h} w2|h|
            acc = __builtin_amdgcn_mfma_f32_16x16x32_f16(A2, W2r[q], acc, 0, 0, 0);
        }

        // cross-wave reduce: lane(col<4) holds b_local = kg*4+col in reg col
        if (col < 4) {
            float v = (col == 0) ? acc[0] : (col == 1) ? acc[1]
                    : (col == 2) ? acc[2] : acc[3];
            smred[j & 1][w * 16 + kg * 4 + col] = v;
        }
        __syncthreads();
        if (tid < 16) {
            const float* r = smred[j & 1];
            out[(size_t)(tile * 16 + tid) * O_DIM + o] =
                r[tid] + r[16 + tid] + r[32 + tid] + r[48 + tid];
        }
    }
}

extern "C" void kernel_launch(void* const* d_in, const int* in_sizes, int n_in,
                              void* d_out, int out_size, void* d_ws, size_t ws_size,
                              hipStream_t stream) {
    const float* x  = (const float*)d_in[0];
    const float* W1 = (const float*)d_in[1];
    const float* b1 = (const float*)d_in[2];
    const float* W2 = (const float*)d_in[3];
    const float* b2 = (const float*)d_in[4];
    float* out = (float*)d_out;
    char* ws = (char*)d_ws;

    ushort* a1f  = (ushort*)(ws + A1F_OFF);
    ushort* w2f  = (ushort*)(ws + W2F_OFF);
    ushort* vl   = (ushort*)(ws + VL_OFF);
    float*  c0b2 = (float*)(ws + C0_OFF);

    prep_all<<<208, 256, 0, stream>>>(W1, b1, W2, b2, a1f, w2f, vl, c0b2);
    mlp_main<<<1024, 256, 0, stream>>>(x, a1f, w2f, vl, c0b2, b1, out);
}

// Round 12
// 27.749 us; speedup vs baseline: 1.2932x; 1.2932x over previous
//
#include <hip/hip_runtime.h>

// out[b,o] = sum_h W2[o,h]*leaky(h) + b2[o],  h = W1[o]·x[b] + b1[o]
// leaky(t) = 0.6t + 0.4|t|
//   out[b,o] = 0.6(v[o]·x[b] + c0[o]) + b2[o] + sum_h (0.4 W2[o,h])|h|
// R13: ONE fused kernel, 512 blocks x 512 thr. Theory: all rounds were bound
// by workgroup delivery/drain (~15ns/WG fits R1-R11; Occ 16% with 16 waves/CU
// launched), not by any pipe. So: fewest WGs that still fill (2 blocks/CU),
// prep fused into each block (per-o fragment staging from W1/W2/b1 directly).
// Inner loop = R9: stage1 mfma16 K=16 exact (b1 via f32-C), stage2 mfma32
// (verified k->h permutation), linear part as acc-init MFMA.

#define B_DIM 32768
#define I_DIM 16
#define O_DIM 16
#define H_DIM 512

typedef _Float16 f16x4 __attribute__((ext_vector_type(4)));
typedef _Float16 f16x8 __attribute__((ext_vector_type(8)));
typedef __fp16   h16x2 __attribute__((ext_vector_type(2)));   // cvt_pkrtz native
typedef float    f32x4 __attribute__((ext_vector_type(4)));
typedef int      i32x2 __attribute__((ext_vector_type(2)));
typedef int      i32x4 __attribute__((ext_vector_type(4)));

// 512 blocks x 512 thr (8 waves), __launch_bounds__(512,4) -> VGPR<=128,
// 2 blocks/CU co-resident (grid == capacity). o = blk&15, grp = blk>>4 (32).
// Block covers 64 b-tiles [grp*64, grp*64+64); wave w: 8 tiles.
__global__ __launch_bounds__(512, 4) void mlp_fused(
    const float* __restrict__ x, const float* __restrict__ W1,
    const float* __restrict__ b1, const float* __restrict__ W2,
    const float* __restrict__ b2, float* __restrict__ out) {
    __shared__ f16x8 sm_a1[1024];     // [p][lane] stage1-A pairs   16 KiB
    __shared__ f16x8 sm_w2[1024];     // [p][lane] stage2-B (0.4x)  16 KiB
    __shared__ float sm_b1[512];      //  2 KiB
    __shared__ float red[512];        //  2 KiB scratch
    __shared__ float v_sm[16];
    __shared__ float c_sm;

    const int tid = threadIdx.x;
    const int o   = blockIdx.x & 15;
    const int grp = blockIdx.x >> 4;
    const float* W1o = W1 + (size_t)o * H_DIM * I_DIM;
    const float* W2o = W2 + (size_t)o * H_DIM;
    const float* b1o = b1 + (size_t)o * H_DIM;

    // ---- phase A: stage fragments (2 entries per table per thread) ----
#pragma unroll
    for (int i = 0; i < 2; ++i) {
        const int e = tid + 512 * i;          // 0..1023 = [p][lane]
        const int l = e & 63, p = e >> 6;
        const int row = l & 15, kg = l >> 4;
        // stage1-A pair: ct=2p (elems 0-3), ct=2p+1 (elems 4-7)
        const float* a_base = W1o + ((size_t)(2 * p * 16 + row) * I_DIM + kg * 4);
        const f32x4 a0 = *reinterpret_cast<const f32x4*>(a_base);
        const f32x4 a1v = *reinterpret_cast<const f32x4*>(a_base + 16 * I_DIM);
        f16x8 va;
#pragma unroll
        for (int j = 0; j < 4; ++j) { va[j] = (_Float16)a0[j]; va[4 + j] = (_Float16)a1v[j]; }
        sm_a1[e] = va;
        // stage2-B: k=kg*8+j -> h = p*32 + ((j>>2)&1)*16 + kg*4 + (j&3)
        const float* w_base = W2o + p * 32 + kg * 4;
        const f32x4 w0 = *reinterpret_cast<const f32x4*>(w_base);
        const f32x4 w1v = *reinterpret_cast<const f32x4*>(w_base + 16);
        f16x8 vw;
#pragma unroll
        for (int j = 0; j < 4; ++j) {
            vw[j]     = (_Float16)(0.4f * w0[j]);
            vw[4 + j] = (_Float16)(0.4f * w1v[j]);
        }
        sm_w2[e] = vw;
    }
    sm_b1[tid] = b1o[tid];

    // ---- phase A2: v[i] = 0.6 sum_h W2[h]W1[h,i]; c0 = 0.6 sum W2 b1 + b2 ----
    {
        const int i = tid & 15, hc = tid >> 4;     // 32 chunks x 16 h
        float acc = 0.f;
#pragma unroll
        for (int hh = 0; hh < 16; ++hh) {
            const int h = hc * 16 + hh;
            acc = fmaf(W2o[h], W1o[(size_t)h * I_DIM + i], acc);
        }
        red[tid] = acc;
    }
    __syncthreads();
    if (tid < 16) {
        float s = 0.f;
#pragma unroll
        for (int k = 0; k < 32; ++k) s += red[tid + 16 * k];
        v_sm[tid] = 0.6f * s;
    }
    float cpart = W2o[tid] * b1o[tid];
    __syncthreads();
    red[tid] = cpart;
    __syncthreads();
    if (tid < 64) {
        float s = 0.f;
#pragma unroll
        for (int k = 0; k < 8; ++k) s += red[tid + 64 * k];
#pragma unroll
        for (int m = 1; m <= 32; m <<= 1) s += __shfl_xor(s, m, 64);
        if (tid == 0) c_sm = 0.6f * s + b2[o];
    }
    __syncthreads();

    // ---- phase B: R9 inner loop, 8 tiles per wave ----
    const int lane = tid & 63, w = tid >> 6;
    const int col = lane & 15, kg = lane >> 4;
    const int tile0 = grp * 64 + w * 8;

    f16x4 xf[8];
#pragma unroll
    for (int t = 0; t < 8; ++t) {
        const f32x4 xr = *reinterpret_cast<const f32x4*>(
            x + (size_t)((tile0 + t) * 16 + col) * I_DIM + kg * 4);
        h16x2 q0 = __builtin_amdgcn_cvt_pkrtz(xr[0], xr[1]);
        h16x2 q1 = __builtin_amdgcn_cvt_pkrtz(xr[2], xr[3]);
        i32x2 xi; xi[0] = __builtin_bit_cast(int, q0); xi[1] = __builtin_bit_cast(int, q1);
        xf[t] = __builtin_bit_cast(f16x4, xi);
    }

    f16x4 vlf;
#pragma unroll
    for (int j = 0; j < 4; ++j) vlf[j] = (_Float16)v_sm[kg * 4 + j];
    const float c0 = c_sm;
    const f32x4 linC = {c0, c0, c0, c0};

    f32x4 acc[8];
#pragma unroll
    for (int t = 0; t < 8; ++t)
        acc[t] = __builtin_amdgcn_mfma_f32_16x16x16f16(xf[t], vlf, linC, 0, 0, 0);

#pragma unroll 2
    for (int p = 0; p < 16; ++p) {
        const f16x8 a1pair = sm_a1[p * 64 + lane];
        const f16x4 A1a = __builtin_shufflevector(a1pair, a1pair, 0, 1, 2, 3);
        const f16x4 A1b = __builtin_shufflevector(a1pair, a1pair, 4, 5, 6, 7);
        const f16x8 W2f = sm_w2[p * 64 + lane];
        const f32x4 bC0 = *reinterpret_cast<const f32x4*>(&sm_b1[p * 32 + kg * 4]);
        const f32x4 bC1 = *reinterpret_cast<const f32x4*>(&sm_b1[p * 32 + 16 + kg * 4]);
#pragma unroll
        for (int t = 0; t < 8; ++t) {
            f32x4 d0 = __builtin_amdgcn_mfma_f32_16x16x16f16(A1a, xf[t], bC0, 0, 0, 0);
            f32x4 d1 = __builtin_amdgcn_mfma_f32_16x16x16f16(A1b, xf[t], bC1, 0, 0, 0);
            h16x2 p0 = __builtin_amdgcn_cvt_pkrtz(fabsf(d0[0]), fabsf(d0[1]));
            h16x2 p1 = __builtin_amdgcn_cvt_pkrtz(fabsf(d0[2]), fabsf(d0[3]));
            h16x2 p2 = __builtin_amdgcn_cvt_pkrtz(fabsf(d1[0]), fabsf(d1[1]));
            h16x2 p3 = __builtin_amdgcn_cvt_pkrtz(fabsf(d1[2]), fabsf(d1[3]));
            i32x4 ai;
            ai[0] = __builtin_bit_cast(int, p0); ai[1] = __builtin_bit_cast(int, p1);
            ai[2] = __builtin_bit_cast(int, p2); ai[3] = __builtin_bit_cast(int, p3);
            f16x8 A2 = __builtin_bit_cast(f16x8, ai);
            acc[t] = __builtin_amdgcn_mfma_f32_16x16x32_f16(A2, W2f, acc[t], 0, 0, 0);
        }
    }

    // acc[t][r]: b_local = kg*4 + r (all 16 cols identical).
    if (col < 4) {
#pragma unroll
        for (int t = 0; t < 8; ++t) {
            float v = (col == 0) ? acc[t][0] : (col == 1) ? acc[t][1]
                    : (col == 2) ? acc[t][2] : acc[t][3];
            out[(size_t)((tile0 + t) * 16 + kg * 4 + col) * O_DIM + o] = v;
        }
    }
}

extern "C" void kernel_launch(void* const* d_in, const int* in_sizes, int n_in,
                              void* d_out, int out_size, void* d_ws, size_t ws_size,
                              hipStream_t stream) {
    const float* x  = (const float*)d_in[0];
    const float* W1 = (const float*)d_in[1];
    const float* b1 = (const float*)d_in[2];
    const float* W2 = (const float*)d_in[3];
    const float* b2 = (const float*)d_in[4];
    float* out = (float*)d_out;

    mlp_fused<<<512, 512, 0, stream>>>(x, W1, b1, W2, b2, out);
}